// Round 10
// baseline (218.748 us; speedup 1.0000x reference)
//
#include <hip/hip_runtime.h>
#include <math.h>

static constexpr int  Bb = 8;
static constexpr int  L  = 2048;
static constexpr int  H  = 256;
static constexpr long BL = (long)Bb * L;     // 16384
static constexpr long LH = (long)L * H;      // 524288
static constexpr long LL = (long)L * L;      // 4194304
static constexpr int  NCH = 16;              // i-tiles of K2 = stats chunks

typedef __attribute__((ext_vector_type(8))) unsigned short u16x8;
typedef __attribute__((ext_vector_type(4))) unsigned short u16x4;
typedef __attribute__((ext_vector_type(8))) _Float16       f16x8;
typedef __attribute__((ext_vector_type(4))) float          f32x4;

__device__ __forceinline__ unsigned short f2hu(float x) {
    union { _Float16 h; unsigned short u; } v; v.h = (_Float16)x; return v.u;
}
__device__ __forceinline__ float hu2f(unsigned short u) {
    union { unsigned short u; _Float16 h; } v; v.u = u; return (float)v.h;
}
__device__ __forceinline__ void gl_lds16(const unsigned short* g, unsigned short* l) {
    __builtin_amdgcn_global_load_lds(
        (const __attribute__((address_space(1))) unsigned int*)g,
        (__attribute__((address_space(3))) unsigned int*)l, 16, 0, 0);
}

// ---------------------------------------------------------------------------
// convert fp32 -> fp16
// ---------------------------------------------------------------------------
__global__ __launch_bounds__(256)
void cvt_g(const float* __restrict__ x, unsigned short* __restrict__ h)
{
    const long i = ((long)blockIdx.x * 256 + threadIdx.x) * 4;
    float4 v = *(const float4*)(x + i);
    u16x4 o;
    o[0] = f2hu(v.x); o[1] = f2hu(v.y); o[2] = f2hu(v.z); o[3] = f2hu(v.w);
    *(u16x4*)(h + i) = o;
}

// WP (blocks [0,64)) + W_out (blocks [64,256)) in one launch
__global__ __launch_bounds__(256)
void cvt_two(const float* __restrict__ x1, unsigned short* __restrict__ h1,
             const float* __restrict__ x2, unsigned short* __restrict__ h2)
{
    const float* x; unsigned short* hp; long base;
    if (blockIdx.x < 64) { x = x1; hp = h1; base = (long)blockIdx.x * 1024; }
    else { x = x2; hp = h2; base = (long)(blockIdx.x - 64) * 1024; }
    const long i = base + (long)threadIdx.x * 4;
    float4 v = *(const float4*)(x + i);
    u16x4 o;
    o[0] = f2hu(v.x); o[1] = f2hu(v.y); o[2] = f2hu(v.z); o[3] = f2hu(v.w);
    *(u16x4*)(hp + i) = o;
}

// ---------------------------------------------------------------------------
// 32x32-tiled fp16 transpose per batch: gT[b][h][j] = g[b][j][h]
// ---------------------------------------------------------------------------
__global__ __launch_bounds__(256)
void transpose_h16(const unsigned short* __restrict__ in, unsigned short* __restrict__ out)
{
    __shared__ unsigned short T[32][33];
    const int b = blockIdx.z, j0 = blockIdx.x * 32, h0 = blockIdx.y * 32;
    const int t = threadIdx.x, r = t >> 3, c4 = (t & 7) << 2;
    const unsigned short* inb = in + (long)b * LH;
    unsigned short* outb = out + (long)b * LH;
    u16x4 v = *(const u16x4*)(inb + (long)(j0 + r) * H + h0 + c4);
#pragma unroll
    for (int e = 0; e < 4; ++e) T[r][c4 + e] = v[e];
    __syncthreads();
    u16x4 w;
#pragma unroll
    for (int e = 0; e < 4; ++e) w[e] = T[c4 + e][r];
    *(u16x4*)(outb + (long)(h0 + r) * L + j0 + c4) = w;
}

// ---------------------------------------------------------------------------
// combine per-chunk column stats -> rescale factors r[c][j] = exp(m_c-m)*zi
// ---------------------------------------------------------------------------
__global__ __launch_bounds__(256)
void col_stats_r(const float* __restrict__ pm, const float* __restrict__ pz,
                 float* __restrict__ rfac)
{
    const long idx = (long)blockIdx.x * 256 + threadIdx.x;   // b*L + j
    const long b = idx / L, j = idx - b * L;
    const float* pmb = pm + b * (long)NCH * L + j;
    const float* pzb = pz + b * (long)NCH * L + j;
    float m = -1e30f;
#pragma unroll
    for (int c = 0; c < NCH; ++c) m = fmaxf(m, pmb[(long)c * L]);
    float z = 0.f;
#pragma unroll
    for (int c = 0; c < NCH; ++c) z += pzb[(long)c * L] * __expf(pmb[(long)c * L] - m);
    const float zi = 1.f / z;
    float* rb = rfac + b * (long)NCH * L + j;
#pragma unroll
    for (int c = 0; c < NCH; ++c) rb[(long)c * L] = __expf(pmb[(long)c * L] - m) * zi;
}

// ---------------------------------------------------------------------------
// Unified NT MFMA GEMM (fp16 inputs), 128x128 tile, NSEG segments of K=256, BK=32.
// MODE 0: P' = fp16(exp(s - m_tile)) + per-chunk stats (K2). global_load_lds.
//         P-write coalesced via padded-LDS bounce.
// MODE 2: fp16 C write (K1: Wh).                              global_load_lds.
// MODE 1: seg2 A synthesized fp16(A0*A1), bias+relu (K5).     reg-staged.
// ---------------------------------------------------------------------------
template<int MODE, int NSEG>
__global__ __launch_bounds__(256)
void mfma_nt(const unsigned short* A0, const unsigned short* A1, const unsigned short* A2,
             const unsigned short* B0, const unsigned short* B1, const unsigned short* B2,
             float* __restrict__ C, unsigned short* __restrict__ Ch,
             float* __restrict__ pm, float* __restrict__ pz,
             const float* __restrict__ bias,
             int N, int lda, int ldb,
             long strideA, long strideB, long strideC)
{
    __shared__ __align__(16) unsigned short As[128][32];
    __shared__ __align__(16) unsigned short Bs[128][32];
    __shared__ float smx[2][128];
    __shared__ float szx[2][128];
    __shared__ float colm[128];
    __shared__ __align__(16) unsigned short Ps[(MODE == 0) ? 128 : 1][136];
    const int tid  = threadIdx.x;
    const int wid  = tid >> 6, lane = tid & 63;
    const int wm   = wid >> 1, wn = wid & 1;
    const long b   = blockIdx.z;
    const int m0   = blockIdx.x * 128, n0 = blockIdx.y * 128;
    const int lrow = tid >> 2, lkc = (tid & 3) << 3;
    const int frow = lane & 15, fk = (lane >> 4) << 3;
    f32x4 acc[4][4];
#pragma unroll
    for (int i = 0; i < 4; ++i)
#pragma unroll
        for (int j = 0; j < 4; ++j) acc[i][j] = (f32x4){0.f, 0.f, 0.f, 0.f};

    const long abase = b * strideA, bbase = b * strideB;
    unsigned short* AsW = &As[0][0] + ((tid >> 6) << 9);   // wave-uniform LDS base
    unsigned short* BsW = &Bs[0][0] + ((tid >> 6) << 9);

    for (int seg = 0; seg < NSEG; ++seg) {
        const unsigned short* Ap = (seg == 0) ? A0 : ((seg == 1) ? A1 : A2);
        const unsigned short* Bp = (seg == 0) ? B0 : ((seg == 1) ? B1 : B2);
        for (int k0 = 0; k0 < 256; k0 += 32) {
            if (MODE == 1) {
                __syncthreads();
#pragma unroll
                for (int r = 0; r < 2; ++r) {
                    const int row = lrow + (r << 6);
                    u16x8 av;
                    if (seg == 2) {
                        const long off = (long)(m0 + row) * lda + k0 + lkc;
                        u16x8 gv = *(const u16x8*)(A0 + off);
                        u16x8 cv = *(const u16x8*)(A1 + off);
#pragma unroll
                        for (int e = 0; e < 8; ++e)
                            av[e] = f2hu(hu2f(gv[e]) * hu2f(cv[e]));
                    } else {
                        av = *(const u16x8*)(Ap + (long)(m0 + row) * lda + k0 + lkc);
                    }
                    *(u16x8*)&As[row][lkc] = av;
                    u16x8 bv = *(const u16x8*)(Bp + (long)(n0 + row) * ldb + k0 + lkc);
                    *(u16x8*)&Bs[row][lkc] = bv;
                }
                __syncthreads();
            } else {
                const unsigned short* Abase = Ap + abase + (long)m0 * lda + k0;
                const unsigned short* Bbase = Bp + bbase + (long)n0 * ldb + k0;
                __syncthreads();
#pragma unroll
                for (int r = 0; r < 2; ++r) {
                    gl_lds16(Abase + (long)(lrow + (r << 6)) * lda + lkc, AsW + (r << 11));
                    gl_lds16(Bbase + (long)(lrow + (r << 6)) * ldb + lkc, BsW + (r << 11));
                }
                __syncthreads();
            }
            f16x8 af[4], bfv[4];
#pragma unroll
            for (int i = 0; i < 4; ++i) af[i]  = *(const f16x8*)&As[wm * 64 + i * 16 + frow][fk];
#pragma unroll
            for (int j = 0; j < 4; ++j) bfv[j] = *(const f16x8*)&Bs[wn * 64 + j * 16 + frow][fk];
#pragma unroll
            for (int i = 0; i < 4; ++i)
#pragma unroll
                for (int j = 0; j < 4; ++j)
                    acc[i][j] = __builtin_amdgcn_mfma_f32_16x16x32_f16(af[i], bfv[j], acc[i][j], 0, 0, 0);
        }
    }

    if (MODE == 0) {
        // --- per-tile column max (over this tile's 128 rows) ---
#pragma unroll
        for (int j = 0; j < 4; ++j) {
            float m = -1e30f;
#pragma unroll
            for (int i = 0; i < 4; ++i)
#pragma unroll
                for (int e = 0; e < 4; ++e) m = fmaxf(m, acc[i][j][e]);
            m = fmaxf(m, __shfl_xor(m, 16));
            m = fmaxf(m, __shfl_xor(m, 32));
            if ((lane >> 4) == 0) smx[wm][wn * 64 + j * 16 + frow] = m;
        }
        __syncthreads();
        if (tid < 128) colm[tid] = fmaxf(smx[0][tid], smx[1][tid]);
        __syncthreads();
        // --- P' = exp(s - m_tile) -> LDS bounce; z partials ---
#pragma unroll
        for (int j = 0; j < 4; ++j) {
            const int colL = wn * 64 + j * 16 + frow;
            const float mm = colm[colL];
            float z = 0.f;
#pragma unroll
            for (int i = 0; i < 4; ++i) {
                const int rl = wm * 64 + i * 16 + ((lane >> 4) << 2);
#pragma unroll
                for (int e = 0; e < 4; ++e) {
                    float p = __expf(acc[i][j][e] - mm);
                    z += p;
                    Ps[rl + e][colL] = f2hu(p);
                }
            }
            z += __shfl_xor(z, 16);
            z += __shfl_xor(z, 32);
            if ((lane >> 4) == 0) szx[wm][colL] = z;
        }
        __syncthreads();
        // --- coalesced P store: 4 rows x 256B per wave-instr ---
        unsigned short* Pb = Ch + b * strideC;
        const int q = lane >> 4, c16 = lane & 15;
#pragma unroll
        for (int e2 = 0; e2 < 8; ++e2) {
            const int rl = e2 * 16 + wid * 4 + q;
            u16x8 v = *(const u16x8*)&Ps[rl][c16 * 8];
            *(u16x8*)(Pb + (long)(m0 + rl) * N + n0 + c16 * 8) = v;
        }
        if (tid < 128) {
            const long o = ((long)b * NCH + blockIdx.x) * L + n0 + tid;
            pm[o] = colm[tid];
            pz[o] = szx[0][tid] + szx[1][tid];
        }
    } else {
#pragma unroll
        for (int i = 0; i < 4; ++i)
#pragma unroll
            for (int j = 0; j < 4; ++j) {
                const int rbase = m0 + wm * 64 + i * 16 + ((lane >> 4) << 2);
                const int col   = n0 + wn * 64 + j * 16 + frow;
                if (MODE == 2) {
#pragma unroll
                    for (int e = 0; e < 4; ++e)
                        Ch[(long)(rbase + e) * N + col] = f2hu(acc[i][j][e]);
                } else {
                    float* Cb = C + b * strideC;
                    const float bv = bias[col];
#pragma unroll
                    for (int e = 0; e < 4; ++e)
                        Cb[(long)(rbase + e) * N + col] = fmaxf(acc[i][j][e] + bv, 0.f);
                }
            }
    }
}

// ---------------------------------------------------------------------------
// attn v5: c[b,i,h] = sum_j (P'[i,j]*r[chunk,j]) * g[j,h]
// Counted-vmcnt pipeline (T4): 4 LDS buffers for gT, raw s_barrier,
// vmcnt(8) steady / vmcnt(0) tail. A (P'*r) in registers (fp16 packed mul).
// B LDS: paired-row [128][64] u16 + XOR swizzle, realized via pre-swizzled
// per-lane GLOBAL source addresses (gl_lds dest stays linear).
// Tile 32(i) x 256(h) x BK=32(j); 256 thr / 4 waves; 512 blocks.
// ---------------------------------------------------------------------------
__global__ __launch_bounds__(256)
void attn_av(const unsigned short* __restrict__ P, const float* __restrict__ rfac,
             const unsigned short* __restrict__ gT, unsigned short* __restrict__ ch)
{
    extern __shared__ unsigned short BsD[];   // 4 x 16384 B
    const int t = threadIdx.x, b = blockIdx.z;
    const int i0 = blockIdx.x * 32;
    const int chunk = i0 >> 7;
    const int w = t >> 6, l = t & 63;
    const int frow = l & 15, fk = (l >> 4) << 3;
    const unsigned short* Pb  = P + (long)b * LL;
    const float* rrow = rfac + ((long)b * NCH + chunk) * L;
    const unsigned short* gTb = gT + (long)b * LH;
    unsigned short* cb = ch + (long)b * LH;

    // B staging: pre-swizzled per-lane global source addresses
    const unsigned short* bsrc[4];
#pragma unroll
    for (int r = 0; r < 4; ++r) {
        const int rp  = r * 32 + (t >> 3);       // LDS row-pair 0..127
        const int q16 = (t & 7) << 3;            // u16 offset within 128B LDS row
        const int ua  = q16 ^ ((rp & 7) << 3);   // inverse swizzle
        const int hh  = rp * 2 + (ua >> 5);
        bsrc[r] = gTb + (long)hh * L + (ua & 31);
    }
    // B frag read offsets (u16, within one buffer), swizzled
    int boff[4];
#pragma unroll
    for (int j4 = 0; j4 < 4; ++j4) {
        const int hrow = w * 64 + j4 * 16 + frow;
        const int rp = hrow >> 1;
        const int u  = ((hrow & 1) << 5) + fk;
        boff[j4] = rp * 64 + (u ^ ((rp & 7) << 3));
    }
    const unsigned short* prow0 = Pb + (long)(i0 + frow) * L + fk;
    const unsigned short* prow1 = Pb + (long)(i0 + 16 + frow) * L + fk;

    f32x4 acc[2][4];
#pragma unroll
    for (int i = 0; i < 2; ++i)
#pragma unroll
        for (int j = 0; j < 4; ++j) acc[i][j] = (f32x4){0.f, 0.f, 0.f, 0.f};

    u16x8 pA0, pA1, pB0, pB1;
    float4 rAa, rAb, rBa, rBb;

#define STAGE_B(BUF, J)                                                     \
    {                                                                       \
        unsigned short* dst = BsD + (BUF) * 8192 + w * 512;                 \
        _Pragma("unroll")                                                   \
        for (int r = 0; r < 4; ++r)                                         \
            gl_lds16(bsrc[r] + (J), dst + r * 2048);                        \
    }

    // ---- prologue: buffers 0,1 in flight; A-reg sets for tiles 0,1 ----
    STAGE_B(0, 0)
    STAGE_B(1, 32)
    __builtin_amdgcn_sched_barrier(0);
    pA0 = *(const u16x8*)(prow0);          pA1 = *(const u16x8*)(prow1);
    rAa = *(const float4*)(rrow + fk);     rAb = *(const float4*)(rrow + fk + 4);
    pB0 = *(const u16x8*)(prow0 + 32);     pB1 = *(const u16x8*)(prow1 + 32);
    rBa = *(const float4*)(rrow + 32 + fk); rBb = *(const float4*)(rrow + 32 + fk + 4);
    __builtin_amdgcn_sched_barrier(0);
    asm volatile("s_waitcnt vmcnt(8)" ::: "memory");
    __builtin_amdgcn_sched_barrier(0);
    __builtin_amdgcn_s_barrier();

#define STEP(PH, C, P0V, P1V, RAV, RBV)                                     \
    {                                                                       \
        const int jS = ((C) + 2) * 32;                                      \
        if (jS < L) STAGE_B(((PH) + 2) & 3, jS)                             \
        __builtin_amdgcn_sched_barrier(0);                                  \
        f16x8 rh;                                                           \
        rh[0] = (_Float16)RAV.x; rh[1] = (_Float16)RAV.y;                   \
        rh[2] = (_Float16)RAV.z; rh[3] = (_Float16)RAV.w;                   \
        rh[4] = (_Float16)RBV.x; rh[5] = (_Float16)RBV.y;                   \
        rh[6] = (_Float16)RBV.z; rh[7] = (_Float16)RBV.w;                   \
        f16x8 a0 = *(f16x8*)&P0V * rh;                                      \
        f16x8 a1 = *(f16x8*)&P1V * rh;                                      \
        _Pragma("unroll")                                                   \
        for (int j4 = 0; j4 < 4; ++j4) {                                    \
            f16x8 bf = *(const f16x8*)(BsD + (PH) * 8192 + boff[j4]);       \
            acc[0][j4] = __builtin_amdgcn_mfma_f32_16x16x32_f16(a0, bf, acc[0][j4], 0, 0, 0); \
            acc[1][j4] = __builtin_amdgcn_mfma_f32_16x16x32_f16(a1, bf, acc[1][j4], 0, 0, 0); \
        }                                                                   \
        if (jS < L) {                                                       \
            P0V = *(const u16x8*)(prow0 + jS);                              \
            P1V = *(const u16x8*)(prow1 + jS);                              \
            RAV = *(const float4*)(rrow + jS + fk);                         \
            RBV = *(const float4*)(rrow + jS + fk + 4);                     \
        }                                                                   \
        __builtin_amdgcn_sched_barrier(0);                                  \
        if ((C) >= 61) { asm volatile("s_waitcnt vmcnt(0)" ::: "memory"); } \
        else           { asm volatile("s_waitcnt vmcnt(8)" ::: "memory"); } \
        __builtin_amdgcn_sched_barrier(0);                                  \
        __builtin_amdgcn_s_barrier();                                       \
    }

    for (int cc = 0; cc < 16; ++cc) {
        const int c0 = cc * 4;
        STEP(0, c0 + 0, pA0, pA1, rAa, rAb)
        STEP(1, c0 + 1, pB0, pB1, rBa, rBb)
        STEP(2, c0 + 2, pA0, pA1, rAa, rAb)
        STEP(3, c0 + 3, pB0, pB1, rBa, rBb)
    }
#undef STEP
#undef STAGE_B

#pragma unroll
    for (int i = 0; i < 2; ++i)
#pragma unroll
        for (int j = 0; j < 4; ++j) {
            const int rbase = i0 + i * 16 + ((l >> 4) << 2);
            const int col   = w * 64 + j * 16 + frow;
#pragma unroll
            for (int e = 0; e < 4; ++e)
                cb[(long)(rbase + e) * H + col] = f2hu(acc[i][j][e]);
        }
}

// ---------------------------------------------------------------------------
extern "C" void kernel_launch(void* const* d_in, const int* in_sizes, int n_in,
                              void* d_out, int out_size, void* d_ws, size_t ws_size,
                              hipStream_t stream)
{
    const float* g     = (const float*)d_in[0];
    const float* WP    = (const float*)d_in[1];
    const float* W_out = (const float*)d_in[2];
    const float* b_out = (const float*)d_in[3];
    float* out = (float*)d_out;

    // ---- workspace layout (bytes), total ~100 MB ----
    char* w = (char*)d_ws;
    unsigned short* P    = (unsigned short*)w;                  // 64 MB  P' fp16
    unsigned short* gh   = (unsigned short*)(w + 67108864);     // 8 MB
    unsigned short* ch   = (unsigned short*)(w + 75497472);     // 8 MB
    unsigned short* gT   = (unsigned short*)(w + 83886080);     // 8 MB
    unsigned short* Whh  = (unsigned short*)(w + 92274688);     // 8 MB
    unsigned short* WPh  = (unsigned short*)(w + 100663296);    // 128 KB
    unsigned short* Woh  = (unsigned short*)(w + 100794368);    // 384 KB
    float*          pm   = (float*)(w + 101187584);             // 1 MB
    float*          pz   = (float*)(w + 102236160);             // 1 MB
    float*          rfac = (float*)(w + 103284736);             // 1 MB

    // 1) converts fp32 -> fp16
    cvt_g<<<dim3((int)(BL * H / 1024)), 256, 0, stream>>>(g, gh);
    cvt_two<<<dim3(256), 256, 0, stream>>>(WP, WPh, W_out, Woh);

    // 2) K1: Wh = g @ WP^T -> fp16
    mfma_nt<2, 1><<<dim3((int)(BL / 128), H / 128, 1), 256, 0, stream>>>(
        gh, nullptr, nullptr, WPh, nullptr, nullptr, nullptr, Whh,
        nullptr, nullptr, nullptr, H, H, H, 0, 0, 0);

    // 3) K2: P'[b] = exp(Wh[b] @ g[b]^T - m_tile) + chunk stats
    mfma_nt<0, 1><<<dim3(L / 128, L / 128, Bb), 256, 0, stream>>>(
        Whh, nullptr, nullptr, gh, nullptr, nullptr, nullptr, P,
        pm, pz, nullptr, L, H, H, LH, LH, LL);

    // 4) rescale factors r[c][j]
    col_stats_r<<<dim3((int)(BL / 256)), 256, 0, stream>>>(pm, pz, rfac);

    // 5) transpose gh -> gT
    transpose_h16<<<dim3(L / 32, H / 32, Bb), 256, 0, stream>>>(gh, gT);

    // 6) attn: c = (P' .* r) @ g -> ch (fp16); 64 KB dynamic LDS
    attn_av<<<dim3(L / 32, 1, Bb), 256, 65536, stream>>>(P, rfac, gT, ch);

    // 7) K5: out = relu([g, c, g*c] @ W_out^T + b)
    mfma_nt<1, 3><<<dim3((int)(BL / 128), H / 128, 1), 256, 0, stream>>>(
        gh, ch, nullptr, Woh, Woh + 256, Woh + 512, out, nullptr,
        nullptr, nullptr, b_out, H, H, 3 * H, 0, 0, 0);
}

// Round 11
// 197.232 us; speedup vs baseline: 1.1091x; 1.1091x over previous
//
#include <hip/hip_runtime.h>
#include <math.h>

static constexpr int  Bb = 8;
static constexpr int  L  = 2048;
static constexpr int  H  = 256;
static constexpr long BL = (long)Bb * L;     // 16384
static constexpr long LH = (long)L * H;      // 524288
static constexpr long LL = (long)L * L;      // 4194304
static constexpr int  NCH = 16;              // i-tiles of K2 = stats chunks

typedef __attribute__((ext_vector_type(8))) unsigned short u16x8;
typedef __attribute__((ext_vector_type(4))) unsigned short u16x4;
typedef __attribute__((ext_vector_type(8))) _Float16       f16x8;
typedef __attribute__((ext_vector_type(4))) float          f32x4;

__device__ __forceinline__ unsigned short f2hu(float x) {
    union { _Float16 h; unsigned short u; } v; v.h = (_Float16)x; return v.u;
}
__device__ __forceinline__ float hu2f(unsigned short u) {
    union { unsigned short u; _Float16 h; } v; v.u = u; return (float)v.h;
}
__device__ __forceinline__ void gl_lds16(const unsigned short* g, unsigned short* l) {
    __builtin_amdgcn_global_load_lds(
        (const __attribute__((address_space(1))) unsigned int*)g,
        (__attribute__((address_space(3))) unsigned int*)l, 16, 0, 0);
}
__device__ __forceinline__ void gl_lds4(const unsigned short* g, unsigned short* l) {
    __builtin_amdgcn_global_load_lds(
        (const __attribute__((address_space(1))) unsigned int*)g,
        (__attribute__((address_space(3))) unsigned int*)l, 4, 0, 0);
}

// ---------------------------------------------------------------------------
// convert fp32 -> fp16
// ---------------------------------------------------------------------------
__global__ __launch_bounds__(256)
void cvt_g(const float* __restrict__ x, unsigned short* __restrict__ h)
{
    const long i = ((long)blockIdx.x * 256 + threadIdx.x) * 4;
    float4 v = *(const float4*)(x + i);
    u16x4 o;
    o[0] = f2hu(v.x); o[1] = f2hu(v.y); o[2] = f2hu(v.z); o[3] = f2hu(v.w);
    *(u16x4*)(h + i) = o;
}

// WP (blocks [0,64)) + W_out (blocks [64,256)) in one launch
__global__ __launch_bounds__(256)
void cvt_two(const float* __restrict__ x1, unsigned short* __restrict__ h1,
             const float* __restrict__ x2, unsigned short* __restrict__ h2)
{
    const float* x; unsigned short* hp; long base;
    if (blockIdx.x < 64) { x = x1; hp = h1; base = (long)blockIdx.x * 1024; }
    else { x = x2; hp = h2; base = (long)(blockIdx.x - 64) * 1024; }
    const long i = base + (long)threadIdx.x * 4;
    float4 v = *(const float4*)(x + i);
    u16x4 o;
    o[0] = f2hu(v.x); o[1] = f2hu(v.y); o[2] = f2hu(v.z); o[3] = f2hu(v.w);
    *(u16x4*)(hp + i) = o;
}

// ---------------------------------------------------------------------------
// 32x32-tiled fp16 transpose per batch: gT[b][h][j] = g[b][j][h]
// ---------------------------------------------------------------------------
__global__ __launch_bounds__(256)
void transpose_h16(const unsigned short* __restrict__ in, unsigned short* __restrict__ out)
{
    __shared__ unsigned short T[32][33];
    const int b = blockIdx.z, j0 = blockIdx.x * 32, h0 = blockIdx.y * 32;
    const int t = threadIdx.x, r = t >> 3, c4 = (t & 7) << 2;
    const unsigned short* inb = in + (long)b * LH;
    unsigned short* outb = out + (long)b * LH;
    u16x4 v = *(const u16x4*)(inb + (long)(j0 + r) * H + h0 + c4);
#pragma unroll
    for (int e = 0; e < 4; ++e) T[r][c4 + e] = v[e];
    __syncthreads();
    u16x4 w;
#pragma unroll
    for (int e = 0; e < 4; ++e) w[e] = T[c4 + e][r];
    *(u16x4*)(outb + (long)(h0 + r) * L + j0 + c4) = w;
}

// ---------------------------------------------------------------------------
// combine per-chunk column stats -> rescale factors r[c][j] = exp(m_c-m)*zi
// ---------------------------------------------------------------------------
__global__ __launch_bounds__(256)
void col_stats_r(const float* __restrict__ pm, const float* __restrict__ pz,
                 float* __restrict__ rfac)
{
    const long idx = (long)blockIdx.x * 256 + threadIdx.x;   // b*L + j
    const long b = idx / L, j = idx - b * L;
    const float* pmb = pm + b * (long)NCH * L + j;
    const float* pzb = pz + b * (long)NCH * L + j;
    float m = -1e30f;
#pragma unroll
    for (int c = 0; c < NCH; ++c) m = fmaxf(m, pmb[(long)c * L]);
    float z = 0.f;
#pragma unroll
    for (int c = 0; c < NCH; ++c) z += pzb[(long)c * L] * __expf(pmb[(long)c * L] - m);
    const float zi = 1.f / z;
    float* rb = rfac + b * (long)NCH * L + j;
#pragma unroll
    for (int c = 0; c < NCH; ++c) rb[(long)c * L] = __expf(pmb[(long)c * L] - m) * zi;
}

// ---------------------------------------------------------------------------
// Unified NT MFMA GEMM (fp16 inputs), 128x128 tile, NSEG segments of K=256, BK=32.
// MODE 0: P' = fp16(exp(s - m_tile)) + per-chunk stats (K2). global_load_lds.
//         P-write coalesced via padded-LDS bounce.
// MODE 2: fp16 C write (K1: Wh).                              global_load_lds.
// MODE 1: seg2 A synthesized fp16(A0*A1), bias+relu (K5).     reg-staged.
// ---------------------------------------------------------------------------
template<int MODE, int NSEG>
__global__ __launch_bounds__(256)
void mfma_nt(const unsigned short* A0, const unsigned short* A1, const unsigned short* A2,
             const unsigned short* B0, const unsigned short* B1, const unsigned short* B2,
             float* __restrict__ C, unsigned short* __restrict__ Ch,
             float* __restrict__ pm, float* __restrict__ pz,
             const float* __restrict__ bias,
             int N, int lda, int ldb,
             long strideA, long strideB, long strideC)
{
    __shared__ __align__(16) unsigned short As[128][32];
    __shared__ __align__(16) unsigned short Bs[128][32];
    __shared__ float smx[2][128];
    __shared__ float szx[2][128];
    __shared__ float colm[128];
    __shared__ __align__(16) unsigned short Ps[(MODE == 0) ? 128 : 1][136];
    const int tid  = threadIdx.x;
    const int wid  = tid >> 6, lane = tid & 63;
    const int wm   = wid >> 1, wn = wid & 1;
    const long b   = blockIdx.z;
    const int m0   = blockIdx.x * 128, n0 = blockIdx.y * 128;
    const int lrow = tid >> 2, lkc = (tid & 3) << 3;
    const int frow = lane & 15, fk = (lane >> 4) << 3;
    f32x4 acc[4][4];
#pragma unroll
    for (int i = 0; i < 4; ++i)
#pragma unroll
        for (int j = 0; j < 4; ++j) acc[i][j] = (f32x4){0.f, 0.f, 0.f, 0.f};

    const long abase = b * strideA, bbase = b * strideB;
    unsigned short* AsW = &As[0][0] + ((tid >> 6) << 9);   // wave-uniform LDS base
    unsigned short* BsW = &Bs[0][0] + ((tid >> 6) << 9);

    for (int seg = 0; seg < NSEG; ++seg) {
        const unsigned short* Ap = (seg == 0) ? A0 : ((seg == 1) ? A1 : A2);
        const unsigned short* Bp = (seg == 0) ? B0 : ((seg == 1) ? B1 : B2);
        for (int k0 = 0; k0 < 256; k0 += 32) {
            if (MODE == 1) {
                __syncthreads();
#pragma unroll
                for (int r = 0; r < 2; ++r) {
                    const int row = lrow + (r << 6);
                    u16x8 av;
                    if (seg == 2) {
                        const long off = (long)(m0 + row) * lda + k0 + lkc;
                        u16x8 gv = *(const u16x8*)(A0 + off);
                        u16x8 cv = *(const u16x8*)(A1 + off);
#pragma unroll
                        for (int e = 0; e < 8; ++e)
                            av[e] = f2hu(hu2f(gv[e]) * hu2f(cv[e]));
                    } else {
                        av = *(const u16x8*)(Ap + (long)(m0 + row) * lda + k0 + lkc);
                    }
                    *(u16x8*)&As[row][lkc] = av;
                    u16x8 bv = *(const u16x8*)(Bp + (long)(n0 + row) * ldb + k0 + lkc);
                    *(u16x8*)&Bs[row][lkc] = bv;
                }
                __syncthreads();
            } else {
                const unsigned short* Abase = Ap + abase + (long)m0 * lda + k0;
                const unsigned short* Bbase = Bp + bbase + (long)n0 * ldb + k0;
                __syncthreads();
#pragma unroll
                for (int r = 0; r < 2; ++r) {
                    gl_lds16(Abase + (long)(lrow + (r << 6)) * lda + lkc, AsW + (r << 11));
                    gl_lds16(Bbase + (long)(lrow + (r << 6)) * ldb + lkc, BsW + (r << 11));
                }
                __syncthreads();
            }
            f16x8 af[4], bfv[4];
#pragma unroll
            for (int i = 0; i < 4; ++i) af[i]  = *(const f16x8*)&As[wm * 64 + i * 16 + frow][fk];
#pragma unroll
            for (int j = 0; j < 4; ++j) bfv[j] = *(const f16x8*)&Bs[wn * 64 + j * 16 + frow][fk];
#pragma unroll
            for (int i = 0; i < 4; ++i)
#pragma unroll
                for (int j = 0; j < 4; ++j)
                    acc[i][j] = __builtin_amdgcn_mfma_f32_16x16x32_f16(af[i], bfv[j], acc[i][j], 0, 0, 0);
        }
    }

    if (MODE == 0) {
        // --- per-tile column max (over this tile's 128 rows) ---
#pragma unroll
        for (int j = 0; j < 4; ++j) {
            float m = -1e30f;
#pragma unroll
            for (int i = 0; i < 4; ++i)
#pragma unroll
                for (int e = 0; e < 4; ++e) m = fmaxf(m, acc[i][j][e]);
            m = fmaxf(m, __shfl_xor(m, 16));
            m = fmaxf(m, __shfl_xor(m, 32));
            if ((lane >> 4) == 0) smx[wm][wn * 64 + j * 16 + frow] = m;
        }
        __syncthreads();
        if (tid < 128) colm[tid] = fmaxf(smx[0][tid], smx[1][tid]);
        __syncthreads();
        // --- P' = exp(s - m_tile) -> LDS bounce; z partials ---
#pragma unroll
        for (int j = 0; j < 4; ++j) {
            const int colL = wn * 64 + j * 16 + frow;
            const float mm = colm[colL];
            float z = 0.f;
#pragma unroll
            for (int i = 0; i < 4; ++i) {
                const int rl = wm * 64 + i * 16 + ((lane >> 4) << 2);
#pragma unroll
                for (int e = 0; e < 4; ++e) {
                    float p = __expf(acc[i][j][e] - mm);
                    z += p;
                    Ps[rl + e][colL] = f2hu(p);
                }
            }
            z += __shfl_xor(z, 16);
            z += __shfl_xor(z, 32);
            if ((lane >> 4) == 0) szx[wm][colL] = z;
        }
        __syncthreads();
        // --- coalesced P store: 4 rows x 256B per wave-instr ---
        unsigned short* Pb = Ch + b * strideC;
        const int q = lane >> 4, c16 = lane & 15;
#pragma unroll
        for (int e2 = 0; e2 < 8; ++e2) {
            const int rl = e2 * 16 + wid * 4 + q;
            u16x8 v = *(const u16x8*)&Ps[rl][c16 * 8];
            *(u16x8*)(Pb + (long)(m0 + rl) * N + n0 + c16 * 8) = v;
        }
        if (tid < 128) {
            const long o = ((long)b * NCH + blockIdx.x) * L + n0 + tid;
            pm[o] = colm[tid];
            pz[o] = szx[0][tid] + szx[1][tid];
        }
    } else {
#pragma unroll
        for (int i = 0; i < 4; ++i)
#pragma unroll
            for (int j = 0; j < 4; ++j) {
                const int rbase = m0 + wm * 64 + i * 16 + ((lane >> 4) << 2);
                const int col   = n0 + wn * 64 + j * 16 + frow;
                if (MODE == 2) {
#pragma unroll
                    for (int e = 0; e < 4; ++e)
                        Ch[(long)(rbase + e) * N + col] = f2hu(acc[i][j][e]);
                } else {
                    float* Cb = C + b * strideC;
                    const float bv = bias[col];
#pragma unroll
                    for (int e = 0; e < 4; ++e)
                        Cb[(long)(rbase + e) * N + col] = fmaxf(acc[i][j][e] + bv, 0.f);
                }
            }
    }
}

// ---------------------------------------------------------------------------
// attn v6: c[b,i,h] = sum_j (P'[i,j]*r[chunk,j]) * g[j,h]
// Both operands staged via global_load_lds with counted vmcnt:
//   B (gT, L2-hot): 2 buffers, staged 1 ahead, rowpair-XOR swizzle (0-conflict).
//   A (P', HBM):    4 buffers, staged 2 ahead, same swizzle, width-4 loads.
//   r: fp16 in LDS once (no VMEM in loop besides counted gl_lds).
// Per step: issue B(C+1)[4] then A(C+2)[2]; wait vmcnt(2); s_barrier.
// Tile 32(i) x 256(h) x BK=32(j); 256 thr / 4 waves; 512 blocks; 44KB LDS.
// ---------------------------------------------------------------------------
__global__ __launch_bounds__(256)
void attn_av(const unsigned short* __restrict__ P, const float* __restrict__ rfac,
             const unsigned short* __restrict__ gT, unsigned short* __restrict__ ch)
{
    extern __shared__ unsigned short LDSD[];
    unsigned short* Bsh = LDSD;              // 2 x 8192 u16 (32 KB)
    unsigned short* Ash = LDSD + 16384;      // 4 x 1024 u16 (8 KB)
    unsigned short* Rs  = LDSD + 20480;      // 2048 u16 (4 KB)
    const int t = threadIdx.x, b = blockIdx.z;
    const int i0 = blockIdx.x * 32;
    const int chunk = i0 >> 7;
    const int w = t >> 6, l = t & 63;
    const int frow = l & 15, fk = (l >> 4) << 3;
    const unsigned short* Pb  = P + (long)b * LL;
    const float* rrow = rfac + ((long)b * NCH + chunk) * L;
    const unsigned short* gTb = gT + (long)b * LH;
    unsigned short* cb = ch + (long)b * LH;

    // B staging: pre-swizzled per-lane global sources (rowpair XOR)
    const unsigned short* bsrc[4];
#pragma unroll
    for (int r = 0; r < 4; ++r) {
        const int rp  = r * 32 + (t >> 3);
        const int q16 = (t & 7) << 3;
        const int ua  = q16 ^ ((rp & 7) << 3);
        bsrc[r] = gTb + (long)(rp * 2 + (ua >> 5)) * L + (ua & 31);
    }
    // A staging: 2 width-4 loads, pre-swizzled sources
    const unsigned short* asrc[2];
#pragma unroll
    for (int ld = 0; ld < 2; ++ld) {
        const int idx = t * 2 + ld * 512;
        const int rp  = idx >> 6;
        const int up  = (idx & 63) ^ ((rp & 7) << 3);
        asrc[ld] = Pb + (long)(i0 + rp * 2 + (up >> 5)) * L + (up & 31);
    }
    // fragment read offsets (u16, swizzled)
    int boff[4];
#pragma unroll
    for (int j4 = 0; j4 < 4; ++j4) {
        const int hrow = w * 64 + j4 * 16 + frow;
        const int rp = hrow >> 1;
        boff[j4] = rp * 64 + ((((hrow & 1) << 5) + fk) ^ ((rp & 7) << 3));
    }
    const int arp   = frow >> 1;
    const int aoff0 = arp * 64 + ((((frow & 1) << 5) + fk) ^ ((arp & 7) << 3));
    const int aoff1 = aoff0 + 512;

    f32x4 acc[2][4];
#pragma unroll
    for (int i = 0; i < 2; ++i)
#pragma unroll
        for (int j = 0; j < 4; ++j) acc[i][j] = (f32x4){0.f, 0.f, 0.f, 0.f};

#define STAGE_B(BUF, J)                                                      \
    {                                                                        \
        unsigned short* d = Bsh + (BUF) * 8192 + w * 512;                    \
        _Pragma("unroll")                                                    \
        for (int r = 0; r < 4; ++r) gl_lds16(bsrc[r] + (J), d + r * 2048);   \
    }
#define STAGE_A(BUF, J)                                                      \
    {                                                                        \
        unsigned short* d = Ash + (BUF) * 1024 + w * 128;                    \
        _Pragma("unroll")                                                    \
        for (int ld = 0; ld < 2; ++ld) gl_lds4(asrc[ld] + (J), d + ld * 512);\
    }

    // ---- prologue: r -> LDS fp16; stage B(0), A(0), A(1) ----
    STAGE_B(0, 0)
    STAGE_A(0, 0)
    STAGE_A(1, 32)
    {
        float4 ra = *(const float4*)(rrow + t * 8);
        float4 rb = *(const float4*)(rrow + t * 8 + 4);
        u16x8 rv;
        rv[0] = f2hu(ra.x); rv[1] = f2hu(ra.y); rv[2] = f2hu(ra.z); rv[3] = f2hu(ra.w);
        rv[4] = f2hu(rb.x); rv[5] = f2hu(rb.y); rv[6] = f2hu(rb.z); rv[7] = f2hu(rb.w);
        *(u16x8*)&Rs[t * 8] = rv;
    }
    asm volatile("s_waitcnt vmcnt(2) lgkmcnt(0)" ::: "memory");
    __builtin_amdgcn_s_barrier();
    __builtin_amdgcn_sched_barrier(0);

#define STEP(K, C)                                                           \
    {                                                                        \
        const int jB = ((C) + 1) * 32, jA = ((C) + 2) * 32;                  \
        if (jB < L) STAGE_B(((K) + 1) & 1, jB)                               \
        if (jA < L) STAGE_A(((K) + 2) & 3, jA)                               \
        f16x8 rh  = *(const f16x8*)&Rs[(C) * 32 + fk];                       \
        f16x8 pa0 = *(const f16x8*)&Ash[((K) & 3) * 1024 + aoff0];           \
        f16x8 pa1 = *(const f16x8*)&Ash[((K) & 3) * 1024 + aoff1];           \
        f16x8 a0 = pa0 * rh, a1 = pa1 * rh;                                  \
        _Pragma("unroll")                                                    \
        for (int j4 = 0; j4 < 4; ++j4) {                                     \
            f16x8 bf = *(const f16x8*)&Bsh[((K) & 1) * 8192 + boff[j4]];     \
            acc[0][j4] = __builtin_amdgcn_mfma_f32_16x16x32_f16(a0, bf, acc[0][j4], 0, 0, 0); \
            acc[1][j4] = __builtin_amdgcn_mfma_f32_16x16x32_f16(a1, bf, acc[1][j4], 0, 0, 0); \
        }                                                                    \
        if (jA < L) { asm volatile("s_waitcnt vmcnt(2)" ::: "memory"); }     \
        else        { asm volatile("s_waitcnt vmcnt(0)" ::: "memory"); }     \
        __builtin_amdgcn_s_barrier();                                        \
        __builtin_amdgcn_sched_barrier(0);                                   \
    }

    for (int cc = 0; cc < 16; ++cc) {
        const int c0 = cc * 4;
        STEP(0, c0 + 0)
        STEP(1, c0 + 1)
        STEP(2, c0 + 2)
        STEP(3, c0 + 3)
    }
#undef STEP
#undef STAGE_B
#undef STAGE_A

#pragma unroll
    for (int i = 0; i < 2; ++i)
#pragma unroll
        for (int j = 0; j < 4; ++j) {
            const int rbase = i0 + i * 16 + ((l >> 4) << 2);
            const int col   = w * 64 + j * 16 + frow;
#pragma unroll
            for (int e = 0; e < 4; ++e)
                cb[(long)(rbase + e) * H + col] = f2hu(acc[i][j][e]);
        }
}

// ---------------------------------------------------------------------------
extern "C" void kernel_launch(void* const* d_in, const int* in_sizes, int n_in,
                              void* d_out, int out_size, void* d_ws, size_t ws_size,
                              hipStream_t stream)
{
    const float* g     = (const float*)d_in[0];
    const float* WP    = (const float*)d_in[1];
    const float* W_out = (const float*)d_in[2];
    const float* b_out = (const float*)d_in[3];
    float* out = (float*)d_out;

    // ---- workspace layout (bytes), total ~100 MB ----
    char* w = (char*)d_ws;
    unsigned short* P    = (unsigned short*)w;                  // 64 MB  P' fp16
    unsigned short* gh   = (unsigned short*)(w + 67108864);     // 8 MB
    unsigned short* ch   = (unsigned short*)(w + 75497472);     // 8 MB
    unsigned short* gT   = (unsigned short*)(w + 83886080);     // 8 MB
    unsigned short* Whh  = (unsigned short*)(w + 92274688);     // 8 MB
    unsigned short* WPh  = (unsigned short*)(w + 100663296);    // 128 KB
    unsigned short* Woh  = (unsigned short*)(w + 100794368);    // 384 KB
    float*          pm   = (float*)(w + 101187584);             // 1 MB
    float*          pz   = (float*)(w + 102236160);             // 1 MB
    float*          rfac = (float*)(w + 103284736);             // 1 MB

    // 1) converts fp32 -> fp16
    cvt_g<<<dim3((int)(BL * H / 1024)), 256, 0, stream>>>(g, gh);
    cvt_two<<<dim3(256), 256, 0, stream>>>(WP, WPh, W_out, Woh);

    // 2) K1: Wh = g @ WP^T -> fp16
    mfma_nt<2, 1><<<dim3((int)(BL / 128), H / 128, 1), 256, 0, stream>>>(
        gh, nullptr, nullptr, WPh, nullptr, nullptr, nullptr, Whh,
        nullptr, nullptr, nullptr, H, H, H, 0, 0, 0);

    // 3) K2: P'[b] = exp(Wh[b] @ g[b]^T - m_tile) + chunk stats
    mfma_nt<0, 1><<<dim3(L / 128, L / 128, Bb), 256, 0, stream>>>(
        Whh, nullptr, nullptr, gh, nullptr, nullptr, nullptr, P,
        pm, pz, nullptr, L, H, H, LH, LH, LL);

    // 4) rescale factors r[c][j]
    col_stats_r<<<dim3((int)(BL / 256)), 256, 0, stream>>>(pm, pz, rfac);

    // 5) transpose gh -> gT
    transpose_h16<<<dim3(L / 32, H / 32, Bb), 256, 0, stream>>>(gh, gT);

    // 6) attn: c = (P' .* r) @ g -> ch (fp16); 44 KB dynamic LDS
    attn_av<<<dim3(L / 32, 1, Bb), 256, 45056, stream>>>(P, rfac, gT, ch);

    // 7) K5: out = relu([g, c, g*c] @ W_out^T + b)
    mfma_nt<1, 3><<<dim3((int)(BL / 128), H / 128, 1), 256, 0, stream>>>(
        gh, ch, nullptr, Woh, Woh + 256, Woh + 512, out, nullptr,
        nullptr, nullptr, b_out, H, H, 3 * H, 0, 0, 0);
}